// Round 5
// baseline (680.200 us; speedup 1.0000x reference)
//
#include <hip/hip_runtime.h>

#define DD 32
#define HH 128
#define WW 128
#define CCH 96
#define NROW (DD*HH)          // 4096
#define NVOX (NROW*WW)        // 524288
#define NTOK 8192
#define NCLU 64

// ---- workspace layout (float offsets) ----
#define Z1_OFF    0ll
#define F_OFF     (9ll*NVOX)                  // 4718592
#define NCP_OFF   (F_OFF + NVOX)              // 5242880  (128 x 4096)
#define ZP_OFF    (NCP_OFF + 128ll*4096)      // 5767168  (128 x 64)
#define SSUM_OFF  (ZP_OFF + 8192)             // 5775360  (64)
#define SINV_OFF  (SSUM_OFF + 64)             // 5775424  (64)
#define CS_OFF    (SINV_OFF + 64)             // 5775488  (4096)
#define QWT_OFF   (CS_OFF + 4096)             // 5779584  (4096)
#define W2T_OFF   (QWT_OFF + 4096)            // 5783680  (2592)
#define NCC_OFF   (W2T_OFF + 2592)            // 5786272  (4096)
#define KT_OFF    (NCC_OFF + 4096)            // 5790368  (4096)
#define VV_OFF    (KT_OFF + 4096)             // 5794464  (4096)
#define O1_OFF    (VV_OFF + 4096)             // 5798560  (524288)
#define WS_FLOATS (O1_OFF + NVOX)             // 6322848

// ============================================================
// K1: channel-split contraction. Thread (half, w) contracts 48 channels of
// voxel (r, w) against its weight half with a 16-channel A/B load pipeline
// (only 8 float4 in flight -> compiler keeps the prefetch). Halves are summed
// during the LDS w-fold. 1 row/block, 4096 blocks.
// ============================================================
__global__ __launch_bounds__(256) void k1_zplanes(
    const float* __restrict__ x, const float* __restrict__ wg,
    float* __restrict__ z1)
{
  __shared__ float csm[2][128][29];   // stride 29 (odd) -> conflict-free
  const int t = threadIdx.x;
  const int half = t >> 7, w = t & 127;   // half is wave-uniform
  const int r = blockIdx.x;               // d*128 + h
  const float* xp = &x[((long)r * WW + w) * CCH + half * 48];
  const float* wbase = &wg[half * 48 * 27];

  float c27[27];
  #pragma unroll
  for (int i = 0; i < 27; ++i) c27[i] = 0.f;

  float4 A0, A1, A2, A3, B0, B1, B2, B3;
  A0 = *(const float4*)(xp + 0); A1 = *(const float4*)(xp + 4);
  A2 = *(const float4*)(xp + 8); A3 = *(const float4*)(xp + 12);

  #pragma unroll
  for (int c0 = 0; c0 < 48; c0 += 16) {
    if (c0 + 16 < 48) {     // prefetch next chunk (compile-time branch)
      B0 = *(const float4*)(xp + c0 + 16);  B1 = *(const float4*)(xp + c0 + 20);
      B2 = *(const float4*)(xp + c0 + 24);  B3 = *(const float4*)(xp + c0 + 28);
    }
    float xs[16];
    *(float4*)&xs[0] = A0; *(float4*)&xs[4] = A1;
    *(float4*)&xs[8] = A2; *(float4*)&xs[12] = A3;
    #pragma unroll
    for (int cc = 0; cc < 16; ++cc) {
      const float* wrow = wbase + (c0 + cc) * 27;  // uniform -> s_load
      const float xc = xs[cc];
      #pragma unroll
      for (int tap = 0; tap < 27; ++tap)
        c27[tap] += xc * wrow[tap];
    }
    A0 = B0; A1 = B1; A2 = B2; A3 = B3;
  }

  #pragma unroll
  for (int tap = 0; tap < 27; ++tap) csm[half][w][tap] = c27[tap];
  __syncthreads();

  // fold w-taps, summing both channel halves; half 0 -> planes 0..3, half 1 -> 4..8
  if (half == 0) {
    #pragma unroll
    for (int j = 0; j < 4; ++j) {
      float s = 0.f;
      #pragma unroll
      for (int kw = 0; kw < 3; ++kw) {
        const int ws = w + kw - 1;
        if (ws >= 0 && ws < 128)
          s += csm[0][ws][j*3 + kw] + csm[1][ws][j*3 + kw];
      }
      z1[(long)j * NVOX + (long)r * WW + w] = s;
    }
  } else {
    #pragma unroll
    for (int j = 4; j < 9; ++j) {
      float s = 0.f;
      #pragma unroll
      for (int kw = 0; kw < 3; ++kw) {
        const int ws = w + kw - 1;
        if (ws >= 0 && ws < 128)
          s += csm[0][ws][j*3 + kw] + csm[1][ws][j*3 + kw];
      }
      z1[(long)j * NVOX + (long)r * WW + w] = s;
    }
  }
}

// ============================================================
// K2: gather 9 shifted planes -> dnx, write token-layout F, accumulate per-f sumsq
// ============================================================
__global__ __launch_bounds__(128) void k2_combine(
    const float* __restrict__ z1, const float* __restrict__ dwc_b,
    float* __restrict__ Fb, float* __restrict__ ssum)
{
  const int r = blockIdx.x;
  const int t = threadIdx.x;
  const int d = r >> 7, h = r & 127;
  float y = dwc_b[0];
  #pragma unroll
  for (int kd = 0; kd < 3; ++kd) {
    const int dd = d + kd - 1;
    if (dd < 0 || dd >= DD) continue;
    #pragma unroll
    for (int kh = 0; kh < 3; ++kh) {
      const int h2 = h + kh - 1;
      if (h2 < 0 || h2 >= HH) continue;
      y += z1[(long)(kd*3+kh)*NVOX + (long)(dd*HH + h2)*WW + t];
    }
  }
  const int n = (d>>2)*1024 + (h>>2)*32 + (t>>2);
  const int f = (d&3)*16 + (h&3)*4 + (t&3);
  Fb[n*64 + f] = y;
  float s = y*y;
  s += __shfl_xor(s, 4);  s += __shfl_xor(s, 8);
  s += __shfl_xor(s, 16); s += __shfl_xor(s, 32);
  if ((t & 63) < 4) atomicAdd(&ssum[(d&3)*16 + (h&3)*4 + (t&3)], s);
}

// ============================================================
// K3: Sinv = 1/max(sqrt(ssum),eps); fold into centroids (Cs) and q_w (QWT, transposed);
//     build transposed upc weights W2T[tap][oc].
// ============================================================
__global__ __launch_bounds__(256) void k3_prep(
    const float* __restrict__ ssum, const float* __restrict__ centroids,
    const float* __restrict__ q_w, const float* __restrict__ upc_w,
    float* __restrict__ sinv, float* __restrict__ cs,
    float* __restrict__ qwt, float* __restrict__ w2t)
{
  __shared__ float sl[64];
  const int t = threadIdx.x;
  if (t < 64) {
    float v = 1.f / fmaxf(sqrtf(ssum[t]), 1e-12f);
    sinv[t] = v; sl[t] = v;
  }
  __syncthreads();
  for (int i = t; i < 4096; i += 256) cs[i] = centroids[i] * sl[i & 63];
  for (int i = t; i < 4096; i += 256) {
    int f = i >> 6, j = i & 63;
    qwt[i] = q_w[j*64 + f] * sl[f];
  }
  for (int i = t; i < 2592; i += 256) {
    int tap = i / 96, oc = i % 96;
    w2t[i] = upc_w[oc*27 + tap];
  }
}

// ============================================================
// K4: 512 blocks: block b -> chunk nb = b>>2 (64 tokens), k-quarter K0 = (b&3)*16.
// ============================================================
__global__ __launch_bounds__(256) void k4_assign(
    const float* __restrict__ Fb, const float* __restrict__ cs,
    float* __restrict__ ncpart, float* __restrict__ zpart)
{
  __shared__ float Fl[64][65], Csl[16][65], El[64][17];
  const int t = threadIdx.x;
  const int nb = blockIdx.x >> 2, K0 = (blockIdx.x & 3) * 16;
  for (int i = t; i < 4096; i += 256) Fl[i>>6][i&63] = Fb[nb*4096 + i];
  for (int i = t; i < 1024; i += 256) Csl[i>>6][i&63] = cs[(K0 + (i>>6))*64 + (i&63)];
  __syncthreads();
  { // phase A
    const int n = t & 63, kk = (t >> 6) * 4;
    float a[4] = {0.f, 0.f, 0.f, 0.f};
    #pragma unroll 8
    for (int f = 0; f < 64; ++f) {
      const float fv = Fl[n][f];
      #pragma unroll
      for (int i = 0; i < 4; ++i) a[i] += fv * Csl[kk+i][f];
    }
    #pragma unroll
    for (int i = 0; i < 4; ++i) El[n][kk+i] = __expf(a[i]);
  }
  __syncthreads();
  { // phase B
    const int f = t & 63, kq = (t >> 6) * 4;
    float acc[4] = {0.f,0.f,0.f,0.f}, za[4] = {0.f,0.f,0.f,0.f};
    for (int n = 0; n < 64; ++n) {
      const float fv = Fl[n][f];
      #pragma unroll
      for (int i = 0; i < 4; ++i) {
        const float ev = El[n][kq+i];   // wave-uniform -> broadcast
        acc[i] += ev * fv;
        za[i]  += ev;
      }
    }
    #pragma unroll
    for (int i = 0; i < 4; ++i)
      ncpart[(long)nb*4096 + (K0+kq+i)*64 + f] = acc[i];
    if (f == 0) {
      #pragma unroll
      for (int i = 0; i < 4; ++i) zpart[nb*64 + K0+kq+i] = za[i];
    }
  }
}

// ============================================================
// K5a (rewritten): block = one k-row (64 f). 256 threads = 64 f x 4 p-groups;
// each thread sums 32 independent partials (MLP), LDS-combine; Z via
// 128-thread parallel load + wave reduce. Grid 64.
// ============================================================
__global__ __launch_bounds__(256) void k5a_nc(
    const float* __restrict__ ncpart, const float* __restrict__ zpart,
    const float* __restrict__ sinv, float* __restrict__ ncout)
{
  __shared__ float part[4][64];
  __shared__ float zw[4];
  const int t = threadIdx.x, b = blockIdx.x;     // b = k
  const int li = t & 63, pg = t >> 6;
  const int idx = b*64 + li;                     // k*64 + f

  float s = 0.f;
  #pragma unroll 8
  for (int p = pg*32; p < pg*32 + 32; ++p)
    s += ncpart[(long)p*4096 + idx];
  part[pg][li] = s;

  float zv = (t < 128) ? zpart[t*64 + b] : 0.f;
  zv += __shfl_xor(zv, 1);  zv += __shfl_xor(zv, 2);  zv += __shfl_xor(zv, 4);
  zv += __shfl_xor(zv, 8);  zv += __shfl_xor(zv, 16); zv += __shfl_xor(zv, 32);
  if ((t & 63) == 0) zw[t >> 6] = zv;
  __syncthreads();

  if (pg == 0) {
    const float Z = zw[0] + zw[1] + zw[2] + zw[3];
    const float tot = part[0][li] + part[1][li] + part[2][li] + part[3][li];
    ncout[idx] = tot / Z * sinv[li];
  }
}

// ============================================================
// K5b: kv = NC @ kv_w^T + kv_b -> kT[j][k] (pre-scaled 1/8, transposed), v[k][j]
// ============================================================
__global__ __launch_bounds__(256) void k5b_kv(
    const float* __restrict__ nc, const float* __restrict__ kv_w,
    const float* __restrict__ kv_b, float* __restrict__ kt, float* __restrict__ vv)
{
  __shared__ float NCl[64][65];
  const int t = threadIdx.x, b = blockIdx.x;
  for (int i = t; i < 4096; i += 256) NCl[i>>6][i&63] = nc[i];
  __syncthreads();
  const int idx = b*256 + t;     // 0..8191
  const int half = idx >> 12, rr = idx & 4095;
  int k, row;
  if (half == 0) { row = rr >> 6; k = rr & 63; }          // kT[j][k]
  else           { k = rr >> 6;  row = 64 + (rr & 63); }  // v[k][jv]
  float a = kv_b[row];
  #pragma unroll
  for (int c = 0; c < 64; ++c) a += NCl[k][c] * kv_w[row*64 + c];
  if (half == 0) kt[row*64 + k] = a * 0.125f;
  else           vv[k*64 + (row-64)] = a;
}

// ============================================================
// K6: wave-per-token attention.
// ============================================================
__global__ __launch_bounds__(256) void k6_attn(
    const float* __restrict__ Fb, const float* __restrict__ qwt_g,
    const float* __restrict__ kt_g, const float* __restrict__ vv_g,
    const float* __restrict__ q_b, float* __restrict__ o1)
{
  __shared__ float qwt[64][65], kt[64][65], vl[64][65];
  const int t = threadIdx.x, b = blockIdx.x;
  for (int i = t; i < 4096; i += 256) {
    int n = i >> 6, m = i & 63;
    qwt[n][m] = qwt_g[i]; kt[n][m] = kt_g[i]; vl[n][m] = vv_g[i];
  }
  __syncthreads();
  const int lane = t & 63, wid = t >> 6;
  const float qb = q_b[lane];
  for (int it = 0; it < 4; ++it) {
    const int n = b*16 + wid*4 + it;
    const float Fv = Fb[n*64 + lane];
    float q = qb;
    #pragma unroll
    for (int f = 0; f < 64; ++f) q += __shfl(Fv, f) * qwt[f][lane];
    float a = 0.f;
    #pragma unroll
    for (int j = 0; j < 64; ++j) a += __shfl(q, j) * kt[j][lane];
    const float e = __expf(a);
    float s = e;
    s += __shfl_xor(s, 1);  s += __shfl_xor(s, 2);  s += __shfl_xor(s, 4);
    s += __shfl_xor(s, 8);  s += __shfl_xor(s, 16); s += __shfl_xor(s, 32);
    const float attn = e / s;
    float o = 0.f;
    #pragma unroll
    for (int k = 0; k < 64; ++k) o += __shfl(attn, k) * vl[k][lane];
    const int bd = n >> 10, bh = (n >> 5) & 31, bw = n & 31;
    const int pd = lane >> 4, ph = (lane >> 2) & 3, pw = lane & 3;
    o1[((bd*4+pd)*HH + (bh*4+ph))*WW + (bw*4+pw)] = o;
  }
}

// ============================================================
// K7: upc conv (1->96ch) + residual. x loads issued first, folded into acc
// right after the barrier (latency hides under o1 staging; xv regs die early).
// ============================================================
__global__ __launch_bounds__(384) void k7_upc(
    const float* __restrict__ o1, const float* __restrict__ w2t,
    const float* __restrict__ upc_b, const float* __restrict__ x,
    float* __restrict__ out)
{
  __shared__ float ol[9][132];
  const int t = threadIdx.x, r = blockIdx.x;
  const int d = r >> 7, h = r & 127;

  const int oc4 = t % 24, wg = t / 24;   // 24 oc-quads x 16 w-groups
  const int w0 = wg * 8;                 // outputs w0..w0+7
  const long base0 = ((long)r*WW + w0)*CCH + oc4*4;

  // 1) issue residual x loads up-front
  float4 xv[8];
  #pragma unroll
  for (int i = 0; i < 8; ++i)
    xv[i] = *(const float4*)&x[base0 + (long)i*CCH];

  // 2) stage o1 stencil rows (overlaps with x-load latency)
  for (int i = t; i < 9*132; i += 384) {
    const int q = i / 132, wp = i % 132;
    const int kd = q / 3, kh = q % 3;
    const int dd = d + kd - 1, h2 = h + kh - 1, w = wp - 1;
    float v = 0.f;
    if (dd >= 0 && dd < DD && h2 >= 0 && h2 < HH && wp >= 1 && wp <= 128)
      v = o1[((long)(dd*HH + h2))*WW + w];
    ol[q][wp] = v;
  }
  __syncthreads();

  // 3) consume xv immediately: acc = bias + residual (xv regs die here)
  const float4 bias = *(const float4*)&upc_b[oc4*4];
  float4 acc[8];
  #pragma unroll
  for (int i = 0; i < 8; ++i) {
    acc[i].x = bias.x + xv[i].x; acc[i].y = bias.y + xv[i].y;
    acc[i].z = bias.z + xv[i].z; acc[i].w = bias.w + xv[i].w;
  }

  #pragma unroll
  for (int q = 0; q < 9; ++q) {
    float row[10];
    {
      const float4 ra = *(const float4*)&ol[q][w0];
      const float4 rb = *(const float4*)&ol[q][w0+4];
      row[0]=ra.x; row[1]=ra.y; row[2]=ra.z; row[3]=ra.w;
      row[4]=rb.x; row[5]=rb.y; row[6]=rb.z; row[7]=rb.w;
      row[8]=ol[q][w0+8]; row[9]=ol[q][w0+9];
    }
    #pragma unroll
    for (int kw = 0; kw < 3; ++kw) {
      const float4 wv = *(const float4*)&w2t[(q*3+kw)*96 + oc4*4];
      #pragma unroll
      for (int i = 0; i < 8; ++i) {
        const float ov = row[i+kw];
        acc[i].x += ov*wv.x; acc[i].y += ov*wv.y;
        acc[i].z += ov*wv.z; acc[i].w += ov*wv.w;
      }
    }
  }

  #pragma unroll
  for (int i = 0; i < 8; ++i)
    *(float4*)&out[base0 + (long)i*CCH] = acc[i];
}

// ============================================================
extern "C" void kernel_launch(void* const* d_in, const int* in_sizes, int n_in,
                              void* d_out, int out_size, void* d_ws, size_t ws_size,
                              hipStream_t stream) {
  const float* x     = (const float*)d_in[0];
  const float* cent  = (const float*)d_in[1];
  const float* dwc_w = (const float*)d_in[2];
  const float* dwc_b = (const float*)d_in[3];
  const float* upc_w = (const float*)d_in[4];
  const float* upc_b = (const float*)d_in[5];
  const float* q_w   = (const float*)d_in[6];
  const float* q_b   = (const float*)d_in[7];
  const float* kv_w  = (const float*)d_in[8];
  const float* kv_b  = (const float*)d_in[9];
  float* out = (float*)d_out;
  float* ws  = (float*)d_ws;

  if (ws_size < (size_t)WS_FLOATS * sizeof(float)) return;  // need ~25.3 MB scratch

  float* z1     = ws + Z1_OFF;
  float* Fb     = ws + F_OFF;
  float* ncpart = ws + NCP_OFF;
  float* zpart  = ws + ZP_OFF;
  float* ssum   = ws + SSUM_OFF;
  float* sinv   = ws + SINV_OFF;
  float* cs     = ws + CS_OFF;
  float* qwt    = ws + QWT_OFF;
  float* w2t    = ws + W2T_OFF;
  float* nc     = ws + NCC_OFF;
  float* kt     = ws + KT_OFF;
  float* vv     = ws + VV_OFF;
  float* o1     = ws + O1_OFF;

  hipMemsetAsync((void*)ssum, 0, 64*sizeof(float), stream);

  k1_zplanes<<<NROW, 256, 0, stream>>>(x, dwc_w, z1);
  k2_combine<<<NROW, 128, 0, stream>>>(z1, dwc_b, Fb, ssum);
  k3_prep  <<<1, 256, 0, stream>>>(ssum, cent, q_w, upc_w, sinv, cs, qwt, w2t);
  k4_assign<<<512, 256, 0, stream>>>(Fb, cs, ncpart, zpart);
  k5a_nc   <<<64, 256, 0, stream>>>(ncpart, zpart, sinv, nc);
  k5b_kv   <<<32, 256, 0, stream>>>(nc, kv_w, kv_b, kt, vv);
  k6_attn  <<<512, 256, 0, stream>>>(Fb, qwt, kt, vv, q_b, o1);
  k7_upc   <<<NROW, 384, 0, stream>>>(o1, w2t, upc_b, x, out);
}